// Round 1
// baseline (27713.358 us; speedup 1.0000x reference)
//
#include <hip/hip_runtime.h>
#include <hip/hip_bf16.h>
#include <hip/hip_cooperative_groups.h>

namespace cg = cooperative_groups;

typedef __attribute__((ext_vector_type(8))) short short8;
typedef __attribute__((ext_vector_type(4))) float f32x4;

#define T_SEQ 1024
#define BATCH 16
#define HID   1024
#define VOC   8192

__device__ inline ushort f2bf(float f) {
  __hip_bfloat16 h = __float2bfloat16(f);
  return __builtin_bit_cast(ushort, h);
}
__device__ inline float bf2f(ushort u) {
  unsigned x = (unsigned)u << 16;
  return __builtin_bit_cast(float, x);
}

// ---------------- transpose Wx + fold bias: WxT[v][i] = Wx[i][v] + bias[i] ----
__global__ void k_wxt(const float* __restrict__ Wx, const float* __restrict__ Wxb,
                      float* __restrict__ WxT) {
  __shared__ float tl[32][33];
  int tx = threadIdx.x & 31, ty = threadIdx.x >> 5;
  int v0 = blockIdx.x * 32, i0 = blockIdx.y * 32;
#pragma unroll
  for (int d = 0; d < 4; ++d)
    tl[ty + d * 8][tx] = Wx[(size_t)(i0 + ty + d * 8) * VOC + v0 + tx];
  __syncthreads();
  float bias = Wxb[i0 + tx];
#pragma unroll
  for (int d = 0; d < 4; ++d) {
    int vr = ty + d * 8;
    WxT[(size_t)(v0 + vr) * HID + i0 + tx] = tl[tx][vr] + bias;
  }
}

// ---------------- split Wy into bf16 segments [Bh | Bh | Bl] ------------------
__global__ void k_wy3(const float* __restrict__ Wy, ushort* __restrict__ Wy3, int KS) {
  size_t idx = (size_t)blockIdx.x * 256 + threadIdx.x;  // float4 index, 2^21 total
  float4 f4 = ((const float4*)Wy)[idx];
  int v = (int)(idx >> 8);         // 256 float4 per 1024-wide row
  int k = ((int)idx & 255) << 2;
  float f[4] = {f4.x, f4.y, f4.z, f4.w};
  ushort hi[4], lo[4];
#pragma unroll
  for (int j = 0; j < 4; ++j) {
    hi[j] = f2bf(f[j]);
    lo[j] = f2bf(f[j] - bf2f(hi[j]));
  }
  ushort4 h4; h4.x = hi[0]; h4.y = hi[1]; h4.z = hi[2]; h4.w = hi[3];
  size_t base = (size_t)v * KS + k;
  *(ushort4*)(Wy3 + base) = h4;
  if (KS >= 2048) *(ushort4*)(Wy3 + base + 1024) = h4;
  if (KS >= 3072) {
    ushort4 l4; l4.x = lo[0]; l4.y = lo[1]; l4.z = lo[2]; l4.w = lo[3];
    *(ushort4*)(Wy3 + base + 2048) = l4;
  }
}

// ---------------- persistent cooperative scan --------------------------------
// 128 blocks x 256 threads. Block owns 8 output rows (i). Wh rows live in VGPRs
// (128 f32/thread, zero duplication). h staged to LDS with XOR swizzle
// (stride-128B reads are 32-way bank conflicts otherwise).
__global__ void __launch_bounds__(256, 1)
k_scan(const float* __restrict__ WxT, const float* __restrict__ Wh,
       const int* __restrict__ x, const float* __restrict__ h0,
       float* __restrict__ pp, ushort* __restrict__ hs3,
       float* __restrict__ hfinal, int KS) {
  extern __shared__ char smem[];  // 65536 B: hL[16][1024] f32, swizzled
  cg::grid_group grid = cg::this_grid();
  const int tid = threadIdx.x;
  const int jc = tid & 31;          // j-chunk (32 f32 each)
  const int bg = (tid >> 5) & 3;    // batch group of 4
  const int ig = tid >> 7;          // i group of 4
  const int blk = blockIdx.x;       // owns i rows [blk*8, blk*8+8)

  // persistent Wh slice: rows blk*8+ig*4+ii, cols jc*32..+31
  float4 WhR[4][8];
#pragma unroll
  for (int ii = 0; ii < 4; ++ii) {
    const float* wrow = Wh + (size_t)(blk * 8 + ig * 4 + ii) * HID + jc * 32;
#pragma unroll
    for (int q = 0; q < 8; ++q) WhR[ii][q] = ((const float4*)wrow)[q];
  }

  const int i_out = blk * 8 + ig * 4 + (jc >> 2);
  const int b_out = bg * 4 + (jc & 3);

  for (int t = 0; t < T_SEQ; ++t) {
    // ---- stage h_prev into LDS (swizzled, conflict-free) ----
    const float* hsrc = (t == 0) ? h0 : (pp + ((t - 1) & 1) * (BATCH * HID));
#pragma unroll
    for (int q = 0; q < 16; ++q) {
      int idx4 = tid + q * 256;                    // float4 slot, row b = idx4>>8
      float4 v = ((const float4*)hsrc)[idx4];
      int byteoff = idx4 << 4;
      int phys = byteoff ^ ((idx4 & 0x38) << 1);   // ^ ((f>>3 & 7) << 4)
      *(float4*)(smem + phys) = v;
    }
    // ---- prefetch embedding term for finisher lanes (latency hides under compute)
    float e = 0.f;
    if (jc < 16) {
      int xv = x[b_out * T_SEQ + t];
      e = WxT[(size_t)xv * HID + i_out];
    }
    __syncthreads();

    // ---- partial dots: acc[ii][bi] over this thread's 32-j slice ----
    float acc[4][4];
#pragma unroll
    for (int ii = 0; ii < 4; ++ii)
#pragma unroll
      for (int bi = 0; bi < 4; ++bi) acc[ii][bi] = 0.f;

#pragma unroll
    for (int q = 0; q < 8; ++q) {
      float4 h4[4];
#pragma unroll
      for (int bi = 0; bi < 4; ++bi) {
        int f = jc * 8 + q;
        int byteoff = ((bg * 4 + bi) << 12) | (f << 4);
        int phys = byteoff ^ (((f >> 3) & 7) << 4);
        h4[bi] = *(const float4*)(smem + phys);
      }
#pragma unroll
      for (int ii = 0; ii < 4; ++ii)
#pragma unroll
        for (int bi = 0; bi < 4; ++bi) {
          acc[ii][bi] += WhR[ii][q].x * h4[bi].x;
          acc[ii][bi] += WhR[ii][q].y * h4[bi].y;
          acc[ii][bi] += WhR[ii][q].z * h4[bi].z;
          acc[ii][bi] += WhR[ii][q].w * h4[bi].w;
        }
    }

    // ---- butterfly reduce across the 32 j-chunks (stays within 32-lane half) ----
#pragma unroll
    for (int ii = 0; ii < 4; ++ii)
#pragma unroll
      for (int bi = 0; bi < 4; ++bi) {
        float v = acc[ii][bi];
        v += __shfl_xor(v, 1);
        v += __shfl_xor(v, 2);
        v += __shfl_xor(v, 4);
        v += __shfl_xor(v, 8);
        v += __shfl_xor(v, 16);
        acc[ii][bi] = v;
      }

    // ---- finisher: one lane per output, tanh + stores ----
    if (jc < 16) {
      float val = acc[0][0];
#pragma unroll
      for (int ii = 0; ii < 4; ++ii)
#pragma unroll
        for (int bi = 0; bi < 4; ++bi)
          if ((ii * 4 + bi) == jc) val = acc[ii][bi];
      float hv = tanhf(val + e);
      pp[(t & 1) * (BATCH * HID) + b_out * HID + i_out] = hv;
      ushort hi = f2bf(hv);
      ushort lo = f2bf(hv - bf2f(hi));
      size_t r = (size_t)b_out * T_SEQ + t;           // GEMM row = b*T + t
      hs3[r * KS + i_out] = hi;                        // A = [Ah | Al | Ah]
      if (KS >= 2048) hs3[r * KS + 1024 + i_out] = lo;
      if (KS >= 3072) hs3[r * KS + 2048 + i_out] = hi;
      if (t == T_SEQ - 1) hfinal[b_out * HID + i_out] = hv;
    }
    grid.sync();
  }
}

// ---------------- bf16 MFMA GEMM: C[16384,8192] = A[16384,KS] * B[8192,KS]^T + bias
// 128x128 tile, BK=64, 4 waves (2x2), 16x16x32 MFMA, XOR-swizzled LDS.
__global__ void __launch_bounds__(256, 2)
k_gemm(const ushort* __restrict__ A, const ushort* __restrict__ Bm,
       const float* __restrict__ bias, float* __restrict__ C, int KS) {
  __shared__ char As[16384];
  __shared__ char Bs[16384];
  const int tid = threadIdx.x;
  const int lane = tid & 63, wave = tid >> 6;
  const int wm = wave & 1, wn = wave >> 1;
  const int bm = blockIdx.y * 128, bn = blockIdx.x * 128;
  const int srow = tid >> 3;            // staging row 0..31 (+32p)
  const int scol = (tid & 7) << 4;      // staging byte col
  const int nk = KS >> 6;

  const size_t strideA = (size_t)KS * 2;  // bytes per row
  const char* Ag = (const char*)A + (size_t)(bm + srow) * strideA + scol;
  const char* Bg = (const char*)Bm + (size_t)(bn + srow) * strideA + scol;

  f32x4 acc[4][4];
#pragma unroll
  for (int i = 0; i < 4; ++i)
#pragma unroll
    for (int j = 0; j < 4; ++j) acc[i][j] = (f32x4){0.f, 0.f, 0.f, 0.f};

  int4 ar[4], br[4];
#pragma unroll
  for (int p = 0; p < 4; ++p) {
    ar[p] = *(const int4*)(Ag + (size_t)(32 * p) * strideA);
    br[p] = *(const int4*)(Bg + (size_t)(32 * p) * strideA);
  }

  for (int kt = 0; kt < nk; ++kt) {
    __syncthreads();
#pragma unroll
    for (int p = 0; p < 4; ++p) {
      int row = srow + 32 * p;
      int phys = row * 128 + (scol ^ ((row & 7) << 4));
      *(int4*)(As + phys) = ar[p];
      *(int4*)(Bs + phys) = br[p];
    }
    __syncthreads();
    if (kt + 1 < nk) {
      const char* Ag2 = Ag + (size_t)(kt + 1) * 128;
      const char* Bg2 = Bg + (size_t)(kt + 1) * 128;
#pragma unroll
      for (int p = 0; p < 4; ++p) {
        ar[p] = *(const int4*)(Ag2 + (size_t)(32 * p) * strideA);
        br[p] = *(const int4*)(Bg2 + (size_t)(32 * p) * strideA);
      }
    }
#pragma unroll
    for (int kg = 0; kg < 2; ++kg) {
      short8 af[4], bf[4];
#pragma unroll
      for (int mi = 0; mi < 4; ++mi) {
        int row = wm * 64 + mi * 16 + (lane & 15);
        int cb = kg * 64 + ((lane >> 4) << 4);
        int phys = row * 128 + (cb ^ ((row & 7) << 4));
        af[mi] = *(const short8*)(As + phys);
      }
#pragma unroll
      for (int ni = 0; ni < 4; ++ni) {
        int row = wn * 64 + ni * 16 + (lane & 15);
        int cb = kg * 64 + ((lane >> 4) << 4);
        int phys = row * 128 + (cb ^ ((row & 7) << 4));
        bf[ni] = *(const short8*)(Bs + phys);
      }
#pragma unroll
      for (int mi = 0; mi < 4; ++mi)
#pragma unroll
        for (int ni = 0; ni < 4; ++ni)
          acc[mi][ni] = __builtin_amdgcn_mfma_f32_16x16x32_bf16(af[mi], bf[ni],
                                                                acc[mi][ni], 0, 0, 0);
    }
  }

  // epilogue: C/D layout col = lane&15, row = (lane>>4)*4 + reg   [m89-verified]
#pragma unroll
  for (int mi = 0; mi < 4; ++mi) {
    int r0 = bm + wm * 64 + mi * 16 + ((lane >> 4) << 2);
#pragma unroll
    for (int ni = 0; ni < 4; ++ni) {
      int col = bn + wn * 64 + ni * 16 + (lane & 15);
      float bv = bias[col];
      float* cp = C + (size_t)r0 * VOC + col;
#pragma unroll
      for (int rr = 0; rr < 4; ++rr)
        cp[(size_t)rr * VOC] = acc[mi][ni][rr] + bv;
    }
  }
}

// ---------------- host ----------------
extern "C" void kernel_launch(void* const* d_in, const int* in_sizes, int n_in,
                              void* d_out, int out_size, void* d_ws, size_t ws_size,
                              hipStream_t stream) {
  (void)in_sizes; (void)n_in; (void)out_size;
  const int*   x   = (const int*)d_in[0];
  const float* h0  = (const float*)d_in[1];
  const float* Wx  = (const float*)d_in[2];
  const float* Wxb = (const float*)d_in[3];
  const float* Wh  = (const float*)d_in[4];
  const float* Wy  = (const float*)d_in[5];
  const float* Wyb = (const float*)d_in[6];
  float* out = (float*)d_out;

  // workspace tiering: K=3072 ([Ah|Al|Ah]x[Bh|Bh|Bl], ~f32 accuracy) preferred
  auto need = [](int KSv) {
    return (size_t)16384 * KSv * 2 + (size_t)8192 * KSv * 2 + 131072 + 256;
  };
  int KS = (ws_size >= need(3072)) ? 3072 : ((ws_size >= need(2048)) ? 2048 : 1024);

  char* wsp = (char*)d_ws;
  ushort* hs3 = (ushort*)wsp;  wsp += (size_t)16384 * KS * 2;
  ushort* wy3 = (ushort*)wsp;  wsp += (size_t)8192 * KS * 2;
  float*  pp  = (float*)wsp;   wsp += 131072;

  float* WxT    = out;                       // 32MB scratch inside logits region
  float* hfinal = out + (size_t)134217728;   // B*T*V

  k_wxt<<<dim3(VOC / 32, HID / 32), 256, 0, stream>>>(Wx, Wxb, WxT);
  k_wy3<<<dim3(8192), 256, 0, stream>>>(Wy, wy3, KS);

  hipFuncSetAttribute((const void*)k_scan,
                      hipFuncAttributeMaxDynamicSharedMemorySize, 65536);
  const float* WxT_c = WxT;
  void* args[] = {(void*)&WxT_c, (void*)&Wh, (void*)&x, (void*)&h0,
                  (void*)&pp, (void*)&hs3, (void*)&hfinal, (void*)&KS};
  hipLaunchCooperativeKernel((void*)k_scan, dim3(128), dim3(256), args, 65536, stream);

  k_gemm<<<dim3(VOC / 128, 16384 / 128), 256, 0, stream>>>(hs3, wy3, Wyb, out, KS);
}

// Round 3
// 9256.545 us; speedup vs baseline: 2.9939x; 2.9939x over previous
//
#include <hip/hip_runtime.h>
#include <hip/hip_bf16.h>
#include <hip/hip_cooperative_groups.h>

typedef __attribute__((ext_vector_type(8))) short short8;
typedef __attribute__((ext_vector_type(4))) float f32x4;

#define T_SEQ 1024
#define BATCH 16
#define HID   1024
#define VOC   8192

__device__ inline ushort f2bf(float f) {
  __hip_bfloat16 h = __float2bfloat16(f);
  return __builtin_bit_cast(ushort, h);
}
__device__ inline float bf2f(ushort u) {
  unsigned x = (unsigned)u << 16;
  return __builtin_bit_cast(float, x);
}

// agent-scope (sc1) ops: bypass per-XCD L2, serviced at the coherent point ->
// cross-XCD coherent with NO cache flush instructions.
__device__ inline f32x4 ld_agent_x4(const float* p) {
  f32x4 r;
  asm volatile("global_load_dwordx4 %0, %1, off sc1" : "=v"(r) : "v"(p) : "memory");
  return r;
}
__device__ inline void st_agent(float* p, float v) {
  asm volatile("global_store_dword %0, %1, off sc1" : : "v"(p), "v"(v) : "memory");
}

// ---------------- transpose Wx + fold bias: WxT[v][i] = Wx[i][v] + bias[i] ----
__global__ void k_wxt(const float* __restrict__ Wx, const float* __restrict__ Wxb,
                      float* __restrict__ WxT) {
  __shared__ float tl[32][33];
  int tx = threadIdx.x & 31, ty = threadIdx.x >> 5;
  int v0 = blockIdx.x * 32, i0 = blockIdx.y * 32;
#pragma unroll
  for (int d = 0; d < 4; ++d)
    tl[ty + d * 8][tx] = Wx[(size_t)(i0 + ty + d * 8) * VOC + v0 + tx];
  __syncthreads();
  float bias = Wxb[i0 + tx];
#pragma unroll
  for (int d = 0; d < 4; ++d) {
    int vr = ty + d * 8;
    WxT[(size_t)(v0 + vr) * HID + i0 + tx] = tl[tx][vr] + bias;
  }
}

// ---------------- split Wy into bf16 segments [Bh | Bh | Bl] ------------------
__global__ void k_wy3(const float* __restrict__ Wy, ushort* __restrict__ Wy3, int KS) {
  size_t idx = (size_t)blockIdx.x * 256 + threadIdx.x;  // float4 index
  float4 f4 = ((const float4*)Wy)[idx];
  int v = (int)(idx >> 8);
  int k = ((int)idx & 255) << 2;
  float f[4] = {f4.x, f4.y, f4.z, f4.w};
  ushort hi[4], lo[4];
#pragma unroll
  for (int j = 0; j < 4; ++j) {
    hi[j] = f2bf(f[j]);
    lo[j] = f2bf(f[j] - bf2f(hi[j]));
  }
  ushort4 h4; h4.x = hi[0]; h4.y = hi[1]; h4.z = hi[2]; h4.w = hi[3];
  size_t base = (size_t)v * KS + k;
  *(ushort4*)(Wy3 + base) = h4;
  if (KS >= 2048) *(ushort4*)(Wy3 + base + 1024) = h4;
  if (KS >= 3072) {
    ushort4 l4; l4.x = lo[0]; l4.y = lo[1]; l4.z = lo[2]; l4.w = lo[3];
    *(ushort4*)(Wy3 + base + 2048) = l4;
  }
}

// ---------------- persistent scan with fence-free flag sync -------------------
// 128 blocks x 256 threads, Wh in VGPRs (128 f32/thread). Cross-block h state
// and flags travel via sc1 (agent/L3) ops; no grid.sync, no L2 flushes.
__global__ void __launch_bounds__(256, 1)
k_scan(const float* __restrict__ WxT, const float* __restrict__ Wh,
       const int* __restrict__ x, const float* __restrict__ h0,
       float* __restrict__ pp, ushort* __restrict__ hs3,
       float* __restrict__ hfinal, int* __restrict__ flags, int KS) {
  extern __shared__ char smem[];  // 65536 B: h[16][1024] f32, XOR-swizzled
  const int tid = threadIdx.x;
  const int jc = tid & 31;          // j-chunk (32 f32 each)
  const int bg = (tid >> 5) & 3;    // batch group of 4
  const int ig = tid >> 7;          // i group of 4
  const int blk = blockIdx.x;       // owns i rows [blk*8, blk*8+8)

  // persistent Wh slice: rows blk*8+ig*4+ii, cols jc*32..+31
  float4 WhR[4][8];
#pragma unroll
  for (int ii = 0; ii < 4; ++ii) {
    const float* wrow = Wh + (size_t)(blk * 8 + ig * 4 + ii) * HID + jc * 32;
#pragma unroll
    for (int q = 0; q < 8; ++q) WhR[ii][q] = ((const float4*)wrow)[q];
  }

  const int i_out = blk * 8 + ig * 4 + (jc >> 2);
  const int b_out = bg * 4 + (jc & 3);

  for (int t = 0; t < T_SEQ; ++t) {
    // ---- wait for step t-1 publication (value t; 0xAA poison never matches)
    if (t > 0) {
      int* f = flags + (t - 1) * 128 + (tid & 127);
      while (__hip_atomic_load(f, __ATOMIC_RELAXED, __HIP_MEMORY_SCOPE_AGENT) != t) {}
    }
    __syncthreads();

    // ---- pull h_prev coherently (L3), 16 in-flight dwordx4 per thread ----
    const float* hsrc = (t == 0) ? h0 : (pp + ((t - 1) & 1) * (BATCH * HID));
    f32x4 hv[16];
#pragma unroll
    for (int q = 0; q < 16; ++q) {
      int idx4 = tid + q * 256;
      hv[q] = ld_agent_x4(hsrc + (size_t)idx4 * 4);
    }
    // embedding term prefetch (plain cached loads; WxT written by prior kernel)
    float e = 0.f;
    if (jc < 16) {
      int xv = x[b_out * T_SEQ + t];
      e = WxT[(size_t)xv * HID + i_out];
    }
    asm volatile("s_waitcnt vmcnt(0)" ::: "memory");
    __builtin_amdgcn_sched_barrier(0);
#pragma unroll
    for (int q = 0; q < 16; ++q) {
      int idx4 = tid + q * 256;
      int byteoff = idx4 << 4;
      int phys = byteoff ^ ((idx4 & 0x38) << 1);   // ^ ((f>>3 & 7) << 4)
      *(f32x4*)(smem + phys) = hv[q];
    }
    __syncthreads();

    // ---- partial dots over this thread's 32-j slice ----
    float acc[4][4];
#pragma unroll
    for (int ii = 0; ii < 4; ++ii)
#pragma unroll
      for (int bi = 0; bi < 4; ++bi) acc[ii][bi] = 0.f;

#pragma unroll
    for (int q = 0; q < 8; ++q) {
      f32x4 h4[4];
#pragma unroll
      for (int bi = 0; bi < 4; ++bi) {
        int f = jc * 8 + q;
        int byteoff = ((bg * 4 + bi) << 12) | (f << 4);
        int phys = byteoff ^ (((f >> 3) & 7) << 4);
        h4[bi] = *(const f32x4*)(smem + phys);
      }
#pragma unroll
      for (int ii = 0; ii < 4; ++ii)
#pragma unroll
        for (int bi = 0; bi < 4; ++bi) {
          acc[ii][bi] += WhR[ii][q].x * h4[bi][0];
          acc[ii][bi] += WhR[ii][q].y * h4[bi][1];
          acc[ii][bi] += WhR[ii][q].z * h4[bi][2];
          acc[ii][bi] += WhR[ii][q].w * h4[bi][3];
        }
    }

    // ---- butterfly reduce across the 32 j-chunks ----
#pragma unroll
    for (int ii = 0; ii < 4; ++ii)
#pragma unroll
      for (int bi = 0; bi < 4; ++bi) {
        float v = acc[ii][bi];
        v += __shfl_xor(v, 1);
        v += __shfl_xor(v, 2);
        v += __shfl_xor(v, 4);
        v += __shfl_xor(v, 8);
        v += __shfl_xor(v, 16);
        acc[ii][bi] = v;
      }

    // ---- finisher lanes: tanh + publish ----
    if (jc < 16) {
      float val = acc[0][0];
#pragma unroll
      for (int ii = 0; ii < 4; ++ii)
#pragma unroll
        for (int bi = 0; bi < 4; ++bi)
          if ((ii * 4 + bi) == jc) val = acc[ii][bi];
      float hvv = tanhf(val + e);
      st_agent(pp + (t & 1) * (BATCH * HID) + b_out * HID + i_out, hvv);
      ushort hi = f2bf(hvv);
      ushort lo = f2bf(hvv - bf2f(hi));
      size_t r = (size_t)b_out * T_SEQ + t;           // GEMM row = b*T + t
      hs3[r * KS + i_out] = hi;                        // A = [Ah | Al | Ah]
      if (KS >= 2048) hs3[r * KS + 1024 + i_out] = lo;
      if (KS >= 3072) hs3[r * KS + 2048 + i_out] = hi;
      if (t == T_SEQ - 1) hfinal[b_out * HID + i_out] = hvv;
    }
    asm volatile("s_waitcnt vmcnt(0)" ::: "memory");
    __syncthreads();  // all waves' sc1 stores drained before flag publish
    if (tid == 0)
      __hip_atomic_store(flags + t * 128 + blk, t + 1, __ATOMIC_RELAXED,
                         __HIP_MEMORY_SCOPE_AGENT);
  }
}

// ---------------- m97-recipe GEMM: C[16384,8192] = A[16384,KS]*B[8192,KS]^T + bias
// 128x128 tile, BK=64, 4 waves (2x2), global_load_lds width=16, linear LDS,
// single-buffer 2-barrier K-loop.
__global__ void __launch_bounds__(256, 3)
k_gemm(const ushort* __restrict__ A, const ushort* __restrict__ Bm,
       const float* __restrict__ bias, float* __restrict__ C, int KS) {
  __shared__ __align__(1024) char As[16384];  // [128 rows][128 B]
  __shared__ __align__(1024) char Bs[16384];
  const int tid = threadIdx.x;
  const int lane = tid & 63, wave = tid >> 6;
  const int wm = wave & 1, wn = wave >> 1;
  const int bm = blockIdx.y * 128, bn = blockIdx.x * 128;
  const int nk = KS >> 6;
  const size_t strb = (size_t)KS * 2;  // bytes per row

  // staging geometry: chunk c = 1KB = 8 rows; lane l -> row (l>>3), byte (l&7)*16
  const int srow = lane >> 3;
  const int sbyte = (lane & 7) << 4;
  const char* Abase = (const char*)A + (size_t)bm * strb + sbyte;
  const char* Bbase = (const char*)Bm + (size_t)bn * strb + sbyte;

  f32x4 acc[4][4];
#pragma unroll
  for (int i = 0; i < 4; ++i)
#pragma unroll
    for (int j = 0; j < 4; ++j) acc[i][j] = (f32x4){0.f, 0.f, 0.f, 0.f};

  for (int kt = 0; kt < nk; ++kt) {
    __syncthreads();  // previous compute done before overwrite
    const char* Ak = Abase + (size_t)kt * 128;
    const char* Bk = Bbase + (size_t)kt * 128;
#pragma unroll
    for (int c4 = 0; c4 < 4; ++c4) {
      int c = wave * 4 + c4;                 // chunk 0..15 (wave-uniform)
      int row = c * 8 + srow;
      __builtin_amdgcn_global_load_lds(
          (const __attribute__((address_space(1))) void*)(Ak + (size_t)row * strb),
          (__attribute__((address_space(3))) void*)(As + c * 1024), 16, 0, 0);
      __builtin_amdgcn_global_load_lds(
          (const __attribute__((address_space(1))) void*)(Bk + (size_t)row * strb),
          (__attribute__((address_space(3))) void*)(Bs + c * 1024), 16, 0, 0);
    }
    asm volatile("s_waitcnt vmcnt(0)" ::: "memory");
    __syncthreads();
#pragma unroll
    for (int ks = 0; ks < 2; ++ks) {
      short8 af[4], bf[4];
      const int cb = ks * 64 + ((lane >> 4) << 4);
#pragma unroll
      for (int mi = 0; mi < 4; ++mi) {
        int row = wm * 64 + mi * 16 + (lane & 15);
        af[mi] = *(const short8*)(As + row * 128 + cb);
      }
#pragma unroll
      for (int ni = 0; ni < 4; ++ni) {
        int row = wn * 64 + ni * 16 + (lane & 15);
        bf[ni] = *(const short8*)(Bs + row * 128 + cb);
      }
#pragma unroll
      for (int mi = 0; mi < 4; ++mi)
#pragma unroll
        for (int ni = 0; ni < 4; ++ni)
          acc[mi][ni] = __builtin_amdgcn_mfma_f32_16x16x32_bf16(af[mi], bf[ni],
                                                                acc[mi][ni], 0, 0, 0);
    }
  }

  // epilogue: C/D layout col = lane&15, row = (lane>>4)*4 + reg   [m89-verified]
#pragma unroll
  for (int mi = 0; mi < 4; ++mi) {
    int r0 = bm + wm * 64 + mi * 16 + ((lane >> 4) << 2);
#pragma unroll
    for (int ni = 0; ni < 4; ++ni) {
      int col = bn + wn * 64 + ni * 16 + (lane & 15);
      float bv = bias[col];
      float* cp = C + (size_t)r0 * VOC + col;
#pragma unroll
      for (int rr = 0; rr < 4; ++rr)
        cp[(size_t)rr * VOC] = acc[mi][ni][rr] + bv;
    }
  }
}

// ---------------- host ----------------
extern "C" void kernel_launch(void* const* d_in, const int* in_sizes, int n_in,
                              void* d_out, int out_size, void* d_ws, size_t ws_size,
                              hipStream_t stream) {
  (void)in_sizes; (void)n_in; (void)out_size;
  const int*   x   = (const int*)d_in[0];
  const float* h0  = (const float*)d_in[1];
  const float* Wx  = (const float*)d_in[2];
  const float* Wxb = (const float*)d_in[3];
  const float* Wh  = (const float*)d_in[4];
  const float* Wy  = (const float*)d_in[5];
  const float* Wyb = (const float*)d_in[6];
  float* out = (float*)d_out;

  // workspace tiering: K=3072 ([Ah|Al|Ah]x[Bh|Bh|Bl], ~f32 accuracy) preferred
  auto need = [](int KSv) {
    return (size_t)16384 * KSv * 2 + (size_t)8192 * KSv * 2 + 131072 + 256;
  };
  int KS = (ws_size >= need(3072)) ? 3072 : ((ws_size >= need(2048)) ? 2048 : 1024);

  char* wsp = (char*)d_ws;
  ushort* hs3 = (ushort*)wsp;  wsp += (size_t)16384 * KS * 2;
  ushort* wy3 = (ushort*)wsp;  wsp += (size_t)8192 * KS * 2;
  float*  pp  = (float*)wsp;   wsp += 131072;

  float* WxT    = out;                              // [0, 32MB) of logits region
  int*   flags  = (int*)((char*)d_out + 36 * 1024 * 1024);  // 512KB, poisoned != t+1
  float* hfinal = out + (size_t)134217728;          // after B*T*V logits

  k_wxt<<<dim3(VOC / 32, HID / 32), 256, 0, stream>>>(Wx, Wxb, WxT);
  k_wy3<<<dim3(8192), 256, 0, stream>>>(Wy, wy3, KS);

  hipFuncSetAttribute((const void*)k_scan,
                      hipFuncAttributeMaxDynamicSharedMemorySize, 65536);
  const float* WxT_c = WxT;
  void* args[] = {(void*)&WxT_c, (void*)&Wh, (void*)&x, (void*)&h0,
                  (void*)&pp, (void*)&hs3, (void*)&hfinal, (void*)&flags, (void*)&KS};
  hipLaunchCooperativeKernel((void*)k_scan, dim3(128), dim3(256), args, 65536, stream);

  k_gemm<<<dim3(VOC / 128, 16384 / 128), 256, 0, stream>>>(hs3, wy3, Wyb, out, KS);
}